// Round 1
// baseline (239.508 us; speedup 1.0000x reference)
//
#include <hip/hip_runtime.h>

#define B_    4
#define CIN_  64
#define H_    128
#define W_    128
#define COUT_ 64
#define K9    9
#define KPOS  576            // CIN_*K9
#define HW    (H_*W_)
#define NMETA 1152           // K9 * 128 pixels

// One block per (b, ho): 128 output pixels x 64 output channels.
// 256 threads. K-loop: 18 chunks of 32 kpos.
__global__ __launch_bounds__(256, 2)
void dcn_fused_f32(const float* __restrict__ x,
                   const float* __restrict__ offset,
                   const float* __restrict__ mask,
                   const float* __restrict__ weight,
                   const float* __restrict__ bias,
                   float* __restrict__ out)
{
    __shared__ int   mIdx[NMETA][4];   // 18 KB: clamped corner indices (y*W+x)
    __shared__ float mWt [NMETA][4];   // 18 KB: bilinear weights * mask * validity
    __shared__ float vT[32][128];      // 16 KB: v chunk [kpos_local][pixel]
    __shared__ float wT[32][64];       //  8 KB: W chunk transposed [kpos_local][cout]

    const int t   = threadIdx.x;
    const int blk = blockIdx.x;        // b*128 + ho
    const int b   = blk >> 7;
    const int ho  = blk & 127;

    // ---------- phase 1: sampling metadata for this row ----------
    for (int e = t; e < NMETA; e += 256) {
        const int p = e & 127;         // wo
        const int k = e >> 7;          // tap 0..8
        const int obase = ((b*18 + 2*k)*H_ + ho)*W_ + p;
        const float dy = offset[obase];
        const float dx = offset[obase + HW];
        const float m  = mask[((b*K9 + k)*H_ + ho)*W_ + p];
        const float py = dy + (float)(k/3) + (float)(ho - 1);   // PAD=1, STRIDE=1, DIL=1
        const float px = dx + (float)(k%3) + (float)(p  - 1);
        const float y0f = floorf(py);
        const float x0f = floorf(px);
        const float wy = py - y0f;
        const float wx = px - x0f;
        const int y0 = (int)y0f, x0 = (int)x0f;
        const int y1 = y0 + 1,  x1 = x0 + 1;
        const bool vy0 = (y0 >= 0) & (y0 < H_);
        const bool vy1 = (y1 >= 0) & (y1 < H_);
        const bool vx0 = (x0 >= 0) & (x0 < W_);
        const bool vx1 = (x1 >= 0) & (x1 < W_);
        const int cy0 = min(max(y0, 0), H_-1), cy1 = min(max(y1, 0), H_-1);
        const int cx0 = min(max(x0, 0), W_-1), cx1 = min(max(x1, 0), W_-1);
        int4 id; float4 w4;
        id.x = cy0*W_ + cx0;  w4.x = (vy0 && vx0) ? (1.f-wy)*(1.f-wx)*m : 0.f;
        id.y = cy0*W_ + cx1;  w4.y = (vy0 && vx1) ? (1.f-wy)*wx*m       : 0.f;
        id.z = cy1*W_ + cx0;  w4.z = (vy1 && vx0) ? wy*(1.f-wx)*m       : 0.f;
        id.w = cy1*W_ + cx1;  w4.w = (vy1 && vx1) ? wy*wx*m             : 0.f;
        *(int4*)  mIdx[e] = id;
        *(float4*)mWt[e]  = w4;
    }

    float acc[8][4];
    #pragma unroll
    for (int i = 0; i < 8; ++i)
        #pragma unroll
        for (int q = 0; q < 4; ++q) acc[i][q] = 0.f;

    const int px0 = (t & 31) * 4;      // 4 consecutive pixels
    const int co0 = (t >> 5) * 8;      // 8 consecutive cout
    const float* xb = x + b*CIN_*HW;

    for (int cc = 0; cc < 18; ++cc) {
        __syncthreads();               // covers phase-1 on first iter, prior readers after

        // ---- stage W chunk: wT[j][co] = weight[co][cc*32+j] ----
        {
            const int co = t >> 2;
            const int j0 = (t & 3) * 8;
            const float4* wsrc = (const float4*)(weight + co*KPOS + cc*32 + j0);
            const float4 a0 = wsrc[0];
            const float4 a1 = wsrc[1];
            wT[j0+0][co] = a0.x; wT[j0+1][co] = a0.y;
            wT[j0+2][co] = a0.z; wT[j0+3][co] = a0.w;
            wT[j0+4][co] = a1.x; wT[j0+5][co] = a1.y;
            wT[j0+6][co] = a1.z; wT[j0+7][co] = a1.w;
        }

        // ---- stage v chunk: vT[j][p], kpos = cc*32 + j ----
        {
            const int p = t & 127;
            const int jb = t >> 7;     // 0 or 1
            #pragma unroll
            for (int i = 0; i < 16; ++i) {
                const int j    = jb + 2*i;
                const int kpos = cc*32 + j;
                const int c    = (kpos * 7282) >> 16;   // kpos/9 for kpos<576
                const int k    = kpos - c*9;
                const int me   = (k << 7) + p;
                const int4   id = *(const int4*)  mIdx[me];
                const float4 w4 = *(const float4*)mWt[me];
                const float* xc = xb + c*HW;
                vT[j][p] = w4.x * xc[id.x] + w4.y * xc[id.y]
                         + w4.z * xc[id.z] + w4.w * xc[id.w];
            }
        }
        __syncthreads();

        // ---- GEMM micro-tile: 8 co x 4 px per thread ----
        #pragma unroll
        for (int j = 0; j < 32; ++j) {
            const float4 v4 = *(const float4*)&vT[j][px0];
            const float4 w0 = *(const float4*)&wT[j][co0];
            const float4 w1 = *(const float4*)&wT[j][co0+4];
            const float wv[8] = {w0.x, w0.y, w0.z, w0.w, w1.x, w1.y, w1.z, w1.w};
            const float vv[4] = {v4.x, v4.y, v4.z, v4.w};
            #pragma unroll
            for (int i = 0; i < 8; ++i)
                #pragma unroll
                for (int q = 0; q < 4; ++q)
                    acc[i][q] = fmaf(wv[i], vv[q], acc[i][q]);
        }
    }

    // ---------- epilogue ----------
    #pragma unroll
    for (int i = 0; i < 8; ++i) {
        const int co = co0 + i;
        const float bb = bias[co];
        float4 r;
        r.x = acc[i][0] + bb; r.y = acc[i][1] + bb;
        r.z = acc[i][2] + bb; r.w = acc[i][3] + bb;
        *(float4*)&out[((b*COUT_ + co)*H_ + ho)*W_ + px0] = r;
    }
}

extern "C" void kernel_launch(void* const* d_in, const int* in_sizes, int n_in,
                              void* d_out, int out_size, void* d_ws, size_t ws_size,
                              hipStream_t stream)
{
    const float* x      = (const float*)d_in[0];
    const float* offset = (const float*)d_in[1];
    const float* mask   = (const float*)d_in[2];
    const float* weight = (const float*)d_in[3];
    const float* bias   = (const float*)d_in[4];
    float* out = (float*)d_out;

    dim3 grid(B_ * H_);   // 512 blocks: one per (b, ho)
    dim3 block(256);
    dcn_fused_f32<<<grid, block, 0, stream>>>(x, offset, mask, weight, bias, out);
}

// Round 2
// 133.433 us; speedup vs baseline: 1.7950x; 1.7950x over previous
//
#include <hip/hip_runtime.h>

#define B_    4
#define CIN_  64
#define H_    128
#define W_    128
#define COUT_ 64
#define HW    (H_*W_)
#define KPOS  576

typedef __attribute__((ext_vector_type(8))) short bf16x8;
typedef __attribute__((ext_vector_type(4))) float f32x4;

static __device__ __forceinline__ unsigned short f2bf(float f) {
    union { float f; unsigned u; } a; a.f = f;
    unsigned r = a.u + 0x7fffu + ((a.u >> 16) & 1u);   // round-to-nearest-even
    return (unsigned short)(r >> 16);
}

// wt[k][co][c] = bf16(weight[co][c][k]) : 9*64*64 ushorts (73728 B) in d_ws
__global__ void prep_weight_bf16(const float* __restrict__ w,
                                 unsigned short* __restrict__ wt)
{
    const int i = blockIdx.x * 256 + threadIdx.x;
    if (i >= 9 * 64 * 64) return;
    const int k  = i >> 12;
    const int r  = i & 4095;
    const int co = r >> 6;
    const int c  = r & 63;
    wt[i] = f2bf(w[co * KPOS + c * 9 + k]);
}

// One block = 64 output pixels x 64 cout for one (b, ho, half-row).
// K reordered tap-major: kpos = k*64 + c (weight paired identically).
// vP: [px][c] bf16, row stride 72*2=144 B -> conflict-free b128 r/w.
template<int USE_WS>
__global__ __launch_bounds__(256, 5)
void dcn_mfma(const float* __restrict__ x,
              const float* __restrict__ offset,
              const float* __restrict__ mask,
              const float* __restrict__ weight,
              const float* __restrict__ bias,
              const unsigned short* __restrict__ wprep,
              float* __restrict__ out)
{
    __shared__ unsigned short vP[64][72];   // v^T tile for current tap (A operand)
    __shared__ unsigned short Wk[64][72];   // weight[co][c] for current tap (B operand)

    const int t   = threadIdx.x;
    const int blk = blockIdx.x;             // ((b*128 + ho)*2 + xh)
    const int xh  = blk & 1;
    const int ho  = (blk >> 1) & 127;
    const int b   = blk >> 8;
    const int p   = t & 63;                 // pixel within 64-tile
    const int wo  = xh * 64 + p;
    const int cq  = t >> 6;                 // channel quarter == wave id
    const int lane = t & 63;

    f32x4 acc[4];
    #pragma unroll
    for (int i = 0; i < 4; ++i) acc[i] = (f32x4){0.f, 0.f, 0.f, 0.f};

    const float* xb = x + (size_t)(b * CIN_ + cq * 16) * HW;

    for (int k = 0; k < 9; ++k) {
        // ---- per-(tap,pixel) sampling metadata, registers only ----
        const int obase = ((b * 18 + 2 * k) * H_ + ho) * W_ + wo;
        const float dy = offset[obase];
        const float dx = offset[obase + HW];
        const float mm = mask[((b * 9 + k) * H_ + ho) * W_ + wo];
        const float py  = dy + (float)(k / 3) + (float)(ho - 1);   // PAD=1,STRIDE=1,DIL=1
        const float pxx = dx + (float)(k % 3) + (float)(wo - 1);
        const float y0f = floorf(py), x0f = floorf(pxx);
        const float wy = py - y0f, wx = pxx - x0f;
        const int y0 = (int)y0f, x0 = (int)x0f;
        const int y1 = y0 + 1,  x1 = x0 + 1;
        const bool vy0 = (y0 >= 0) & (y0 < H_), vy1 = (y1 >= 0) & (y1 < H_);
        const bool vx0 = (x0 >= 0) & (x0 < W_), vx1 = (x1 >= 0) & (x1 < W_);
        const int cy0 = min(max(y0, 0), H_-1), cy1 = min(max(y1, 0), H_-1);
        const int cx0 = min(max(x0, 0), W_-1), cx1 = min(max(x1, 0), W_-1);
        const int i00 = cy0 * W_ + cx0, i01 = cy0 * W_ + cx1;
        const int i10 = cy1 * W_ + cx0, i11 = cy1 * W_ + cx1;
        const float w00 = (vy0 && vx0) ? (1.f - wy) * (1.f - wx) * mm : 0.f;
        const float w01 = (vy0 && vx1) ? (1.f - wy) * wx * mm         : 0.f;
        const float w10 = (vy1 && vx0) ? wy * (1.f - wx) * mm         : 0.f;
        const float w11 = (vy1 && vx1) ? wy * wx * mm                 : 0.f;

        __syncthreads();   // previous tap's MFMA reads complete

        // ---- stage Wk[co][c] (bf16) for this tap ----
        if (USE_WS) {
            #pragma unroll
            for (int q = 0; q < 2; ++q) {
                const int j  = q * 2048 + t * 8;        // coalesced 16B per lane
                const int co = j >> 6, c0 = j & 63;
                const bf16x8 val = *(const bf16x8*)(wprep + k * 4096 + j);
                *(bf16x8*)&Wk[co][c0] = val;
            }
        } else {
            const int co = t >> 2;
            const int c0 = (t & 3) * 16;
            union { bf16x8 v; unsigned short u[8]; } pk0, pk1;
            #pragma unroll
            for (int i = 0; i < 8; ++i) {
                pk0.u[i] = f2bf(weight[co * KPOS + (c0 + i) * 9 + k]);
                pk1.u[i] = f2bf(weight[co * KPOS + (c0 + 8 + i) * 9 + k]);
            }
            *(bf16x8*)&Wk[co][c0]     = pk0.v;
            *(bf16x8*)&Wk[co][c0 + 8] = pk1.v;
        }

        // ---- gather: 16 channels for this (tap, pixel) ----
        #pragma unroll
        for (int cb = 0; cb < 16; cb += 8) {
            union { bf16x8 v; unsigned short u[8]; } pk;
            #pragma unroll
            for (int u = 0; u < 8; ++u) {
                const float* xp = xb + (size_t)(cb + u) * HW;
                const float v = w00 * xp[i00] + w01 * xp[i01]
                              + w10 * xp[i10] + w11 * xp[i11];
                pk.u[u] = f2bf(v);
            }
            *(bf16x8*)&vP[p][cq * 16 + cb] = pk.v;
        }
        __syncthreads();

        // ---- MFMA: wave cq owns m-tile (16 px), all 4 n-tiles ----
        const int ra = cq * 16 + (lane & 15);
        const int kc = (lane >> 4) * 8;
        #pragma unroll
        for (int ks = 0; ks < 2; ++ks) {
            const int kcol = ks * 32 + kc;
            const bf16x8 a = *(const bf16x8*)&vP[ra][kcol];
            #pragma unroll
            for (int nt = 0; nt < 4; ++nt) {
                const bf16x8 bb = *(const bf16x8*)&Wk[nt * 16 + (lane & 15)][kcol];
                acc[nt] = __builtin_amdgcn_mfma_f32_16x16x32_bf16(a, bb, acc[nt], 0, 0, 0);
            }
        }
    }

    // ---- epilogue: D col = lane&15 (co), row = (lane>>4)*4+r (px) ----
    const int px0 = cq * 16 + (lane >> 4) * 4;
    #pragma unroll
    for (int nt = 0; nt < 4; ++nt) {
        const int co = nt * 16 + (lane & 15);
        const float bb = bias[co];
        float4 r;
        r.x = acc[nt][0] + bb;
        r.y = acc[nt][1] + bb;
        r.z = acc[nt][2] + bb;
        r.w = acc[nt][3] + bb;
        *(float4*)&out[(((size_t)b * COUT_ + co) * H_ + ho) * W_ + xh * 64 + px0] = r;
    }
}

extern "C" void kernel_launch(void* const* d_in, const int* in_sizes, int n_in,
                              void* d_out, int out_size, void* d_ws, size_t ws_size,
                              hipStream_t stream)
{
    const float* x      = (const float*)d_in[0];
    const float* offset = (const float*)d_in[1];
    const float* mask   = (const float*)d_in[2];
    const float* weight = (const float*)d_in[3];
    const float* bias   = (const float*)d_in[4];
    float* out = (float*)d_out;

    dim3 block(256);
    dim3 grid(B_ * H_ * 2);   // 1024 blocks: (b, ho, half-row)

    if (ws_size >= (size_t)(9 * 64 * 64 * sizeof(unsigned short))) {
        unsigned short* wprep = (unsigned short*)d_ws;
        prep_weight_bf16<<<dim3(144), block, 0, stream>>>(weight, wprep);
        dcn_mfma<1><<<grid, block, 0, stream>>>(x, offset, mask, weight, bias, wprep, out);
    } else {
        dcn_mfma<0><<<grid, block, 0, stream>>>(x, offset, mask, weight, bias, nullptr, out);
    }
}

// Round 3
// 123.820 us; speedup vs baseline: 1.9343x; 1.0776x over previous
//
#include <hip/hip_runtime.h>

#define B_    4
#define CIN_  64
#define H_    128
#define W_    128
#define COUT_ 64
#define HW    (H_*W_)
#define KPOS  576

typedef __attribute__((ext_vector_type(8))) short bf16x8;
typedef __attribute__((ext_vector_type(4))) float f32x4;

static __device__ __forceinline__ unsigned short f2bf(float f) {
    union { float f; unsigned u; } a; a.f = f;
    unsigned r = a.u + 0x7fffu + ((a.u >> 16) & 1u);   // RNE
    return (unsigned short)(r >> 16);
}

// wt[k][co][c] = bf16(weight[co][c][k]) : 9*64*64 ushorts (73728 B) in d_ws
__global__ void prep_weight_bf16(const float* __restrict__ w,
                                 unsigned short* __restrict__ wt)
{
    const int i = blockIdx.x * 256 + threadIdx.x;
    if (i >= 9 * 64 * 64) return;
    const int k  = i >> 12;
    const int r  = i & 4095;
    const int co = r >> 6;
    const int c  = r & 63;
    wt[i] = f2bf(w[co * KPOS + c * 9 + k]);
}

// One block = 64 output pixels x 64 cout for one (b, ho, half-row).
// Tap-major K (kpos = k*64+c). Double-buffered LDS, 1 barrier/tap.
// XCD-chunked swizzle: each XCD works 64 consecutive ho rows of one batch.
template<int USE_WS>
__global__ __launch_bounds__(256, 4)
void dcn_mfma(const float* __restrict__ x,
              const float* __restrict__ offset,
              const float* __restrict__ mask,
              const float* __restrict__ weight,
              const float* __restrict__ bias,
              const unsigned short* __restrict__ wprep,
              float* __restrict__ out)
{
    __shared__ unsigned short vP[2][64][72];   // v^T tile (A), dbuf
    __shared__ unsigned short Wk[2][64][72];   // weight tile (B), dbuf

    const int t   = threadIdx.x;
    const int bid = blockIdx.x;
    const int wk  = ((bid & 7) << 7) | (bid >> 3);   // 1024 = 8 XCD * 128 chunk
    const int xh  = wk & 1;
    const int ho  = (wk >> 1) & 127;
    const int b   = wk >> 8;
    const int p   = t & 63;                 // pixel within 64-tile
    const int wo  = xh * 64 + p;
    const int cq  = t >> 6;                 // wave id == channel quarter
    const int lane = t & 63;

    f32x4 acc[4];
    #pragma unroll
    for (int i = 0; i < 4; ++i) acc[i] = (f32x4){0.f, 0.f, 0.f, 0.f};

    const float* xb = x + (size_t)(b * CIN_ + cq * 16) * HW;

    auto stage = [&](int k, int s) {
        // ---- per-(tap,pixel) metadata, registers only ----
        const int obase = ((b * 18 + 2 * k) * H_ + ho) * W_ + wo;
        const float dy = offset[obase];
        const float dx = offset[obase + HW];
        const float mm = mask[((b * 9 + k) * H_ + ho) * W_ + wo];
        const float py  = dy + (float)(k / 3) + (float)(ho - 1);   // PAD=1
        const float pxx = dx + (float)(k % 3) + (float)(wo - 1);
        const float y0f = floorf(py), x0f = floorf(pxx);
        const float wy = py - y0f, wx = pxx - x0f;
        const int y0 = (int)y0f, x0 = (int)x0f;
        const int y1 = y0 + 1,  x1 = x0 + 1;
        const bool vy0 = (y0 >= 0) & (y0 < H_), vy1 = (y1 >= 0) & (y1 < H_);
        const bool vx0 = (x0 >= 0) & (x0 < W_), vx1 = (x1 >= 0) & (x1 < W_);
        const int cy0 = min(max(y0, 0), H_-1), cy1 = min(max(y1, 0), H_-1);
        const int cx0 = min(max(x0, 0), W_-1), cx1 = min(max(x1, 0), W_-1);
        const int i00 = cy0 * W_ + cx0, i01 = cy0 * W_ + cx1;
        const int i10 = cy1 * W_ + cx0, i11 = cy1 * W_ + cx1;
        const float w00 = (vy0 && vx0) ? (1.f - wy) * (1.f - wx) * mm : 0.f;
        const float w01 = (vy0 && vx1) ? (1.f - wy) * wx * mm         : 0.f;
        const float w10 = (vy1 && vx0) ? wy * (1.f - wx) * mm         : 0.f;
        const float w11 = (vy1 && vx1) ? wy * wx * mm                 : 0.f;

        // ---- stage Wk for this tap ----
        if (USE_WS) {
            #pragma unroll
            for (int q = 0; q < 2; ++q) {
                const int j  = q * 2048 + t * 8;
                const int co = j >> 6, c0 = j & 63;
                *(bf16x8*)&Wk[s][co][c0] = *(const bf16x8*)(wprep + k * 4096 + j);
            }
        } else {
            const int co = t >> 2;
            const int c0 = (t & 3) * 16;
            union { bf16x8 v; unsigned short u[8]; } pk0, pk1;
            #pragma unroll
            for (int i = 0; i < 8; ++i) {
                pk0.u[i] = f2bf(weight[co * KPOS + (c0 + i) * 9 + k]);
                pk1.u[i] = f2bf(weight[co * KPOS + (c0 + 8 + i) * 9 + k]);
            }
            *(bf16x8*)&Wk[s][co][c0]     = pk0.v;
            *(bf16x8*)&Wk[s][co][c0 + 8] = pk1.v;
        }

        // ---- gather 16 channels: issue ALL 64 loads first (MLP) ----
        float r[16][4];
        {
            const float* xp = xb;
            #pragma unroll
            for (int c = 0; c < 16; ++c) {
                r[c][0] = xp[i00]; r[c][1] = xp[i01];
                r[c][2] = xp[i10]; r[c][3] = xp[i11];
                xp += HW;
            }
        }
        union { bf16x8 v; unsigned short u[8]; } pk;
        #pragma unroll
        for (int cb = 0; cb < 16; cb += 8) {
            #pragma unroll
            for (int u = 0; u < 8; ++u) {
                const int c = cb + u;
                pk.u[u] = f2bf(w00 * r[c][0] + w01 * r[c][1]
                             + w10 * r[c][2] + w11 * r[c][3]);
            }
            *(bf16x8*)&vP[s][p][cq * 16 + cb] = pk.v;
        }
    };

    auto domfma = [&](int s) {
        const int ra = cq * 16 + (lane & 15);
        const int kc = (lane >> 4) * 8;
        #pragma unroll
        for (int ks = 0; ks < 2; ++ks) {
            const int kcol = ks * 32 + kc;
            const bf16x8 a = *(const bf16x8*)&vP[s][ra][kcol];
            #pragma unroll
            for (int nt = 0; nt < 4; ++nt) {
                const bf16x8 bb = *(const bf16x8*)&Wk[s][nt * 16 + (lane & 15)][kcol];
                acc[nt] = __builtin_amdgcn_mfma_f32_16x16x32_bf16(a, bb, acc[nt], 0, 0, 0);
            }
        }
    };

    stage(0, 0);
    __syncthreads();
    for (int k = 0; k < 9; ++k) {
        const int s = k & 1;
        if (k < 8) stage(k + 1, s ^ 1);   // loads overlap MFMA below
        domfma(s);
        __syncthreads();
    }

    // ---- epilogue: D col = lane&15 (co), row = (lane>>4)*4+j (px) ----
    const int px0 = cq * 16 + (lane >> 4) * 4;
    #pragma unroll
    for (int nt = 0; nt < 4; ++nt) {
        const int co = nt * 16 + (lane & 15);
        const float bb = bias[co];
        float4 r;
        r.x = acc[nt][0] + bb;
        r.y = acc[nt][1] + bb;
        r.z = acc[nt][2] + bb;
        r.w = acc[nt][3] + bb;
        *(float4*)&out[(((size_t)b * COUT_ + co) * H_ + ho) * W_ + xh * 64 + px0] = r;
    }
}

extern "C" void kernel_launch(void* const* d_in, const int* in_sizes, int n_in,
                              void* d_out, int out_size, void* d_ws, size_t ws_size,
                              hipStream_t stream)
{
    const float* x      = (const float*)d_in[0];
    const float* offset = (const float*)d_in[1];
    const float* mask   = (const float*)d_in[2];
    const float* weight = (const float*)d_in[3];
    const float* bias   = (const float*)d_in[4];
    float* out = (float*)d_out;

    dim3 block(256);
    dim3 grid(B_ * H_ * 2);   // 1024 blocks: (b, ho, half-row)

    if (ws_size >= (size_t)(9 * 64 * 64 * sizeof(unsigned short))) {
        unsigned short* wprep = (unsigned short*)d_ws;
        prep_weight_bf16<<<dim3(144), block, 0, stream>>>(weight, wprep);
        dcn_mfma<1><<<grid, block, 0, stream>>>(x, offset, mask, weight, bias, wprep, out);
    } else {
        dcn_mfma<0><<<grid, block, 0, stream>>>(x, offset, mask, weight, bias, nullptr, out);
    }
}

// Round 4
// 49.571 us; speedup vs baseline: 4.8316x; 2.4978x over previous
//
#include <hip/hip_runtime.h>

#define B_    4
#define CIN_  64
#define H_    128
#define W_    128
#define COUT_ 64
#define HW    (H_*W_)
#define KPOS  576

typedef __attribute__((ext_vector_type(8))) short bf16x8;
typedef __attribute__((ext_vector_type(4))) short bf16x4;
typedef __attribute__((ext_vector_type(4))) float f32x4;

static __device__ __forceinline__ unsigned short f2bf(float f) {
    union { float f; unsigned u; } a; a.f = f;
    unsigned r = a.u + 0x7fffu + ((a.u >> 16) & 1u);   // RNE
    return (unsigned short)(r >> 16);
}
static __device__ __forceinline__ float bf2f(unsigned short u) {
    union { unsigned u; float f; } a; a.u = ((unsigned)u) << 16;
    return a.f;
}

#define XT_USHORTS ((size_t)B_ * HW * 64)            // NHWC bf16 image
#define WP_USHORTS ((size_t)9 * 64 * 64)             // wt[k][co][c]
#define WS_NEED    ((XT_USHORTS + WP_USHORTS) * 2)

// ---------------- prep: weight -> bf16, tap-major ----------------
__global__ void prep_weight_bf16(const float* __restrict__ w,
                                 unsigned short* __restrict__ wt)
{
    const int i = blockIdx.x * 256 + threadIdx.x;
    if (i >= 9 * 64 * 64) return;
    const int k  = i >> 12;
    const int r  = i & 4095;
    const int co = r >> 6;
    const int c  = r & 63;
    wt[i] = f2bf(w[co * KPOS + c * 9 + k]);
}

// ---------------- prep: x NCHW f32 -> NHWC bf16 ----------------
__global__ __launch_bounds__(256)
void xpose_bf16(const float* __restrict__ x, unsigned short* __restrict__ xT)
{
    __shared__ unsigned short ld[64 * 132];
    const int t   = threadIdx.x;
    const int blk = blockIdx.x;          // b*128 + y
    const int b   = blk >> 7;
    const int y   = blk & 127;
    const float* src = x + (size_t)b * 64 * HW + y * W_;
    #pragma unroll
    for (int i = 0; i < 8; ++i) {
        const int e4 = (t + i * 256) * 4;      // element c*128 + x0
        const int c  = e4 >> 7;
        const int x0 = e4 & 127;
        const float4 v = *(const float4*)(src + (size_t)c * HW + x0);
        unsigned short* d = &ld[c * 132 + x0];
        d[0] = f2bf(v.x); d[1] = f2bf(v.y); d[2] = f2bf(v.z); d[3] = f2bf(v.w);
    }
    __syncthreads();
    unsigned short* dst = xT + ((size_t)b * HW + (size_t)y * W_) * 64;
    #pragma unroll
    for (int i = 0; i < 4; ++i) {
        const int o    = (t + i * 256) * 8;    // ushort offset: xcol*64 + c0
        const int xcol = o >> 6;
        const int c0   = o & 63;
        union { bf16x8 v; unsigned short u[8]; } pk;
        #pragma unroll
        for (int j = 0; j < 8; ++j) pk.u[j] = ld[(c0 + j) * 132 + xcol];
        *(bf16x8*)(dst + o) = pk.v;
    }
}

// ---------------- main: NHWC gather + MFMA ----------------
// One block = 64 px x 64 cout for one (b, ho, half). Tap-major K.
// Gather: lane = (px_sub<<4)|c4 ; 4 px/iter, 4 iters/tap per wave.
__global__ __launch_bounds__(256, 4)
void dcn_mfma_nhwc(const unsigned short* __restrict__ xT,
                   const float* __restrict__ offset,
                   const float* __restrict__ mask,
                   const float* __restrict__ bias,
                   const unsigned short* __restrict__ wprep,
                   float* __restrict__ out)
{
    __shared__ unsigned short vP[2][64][72];
    __shared__ unsigned short Wk[2][64][72];

    const int t   = threadIdx.x;
    const int bid = blockIdx.x;
    const int wk  = ((bid & 7) << 7) | (bid >> 3);   // XCD-chunked swizzle
    const int xh  = wk & 1;
    const int ho  = (wk >> 1) & 127;
    const int b   = wk >> 8;
    const int cq  = t >> 6;                  // wave id
    const int lane = t & 63;
    const int px_sub = lane >> 4;            // 0..3
    const int c4     = lane & 15;            // channel quad

    f32x4 acc[4];
    #pragma unroll
    for (int i = 0; i < 4; ++i) acc[i] = (f32x4){0.f, 0.f, 0.f, 0.f};

    const unsigned short* xTb = xT + (size_t)b * HW * 64;

    auto stage = [&](int k, int s) {
        // ---- metadata for this lane's 4 pixels (registers) ----
        int   idxs[4][4];
        float wts [4][4];
        #pragma unroll
        for (int it = 0; it < 4; ++it) {
            const int pl = (cq << 4) | (it << 2) | px_sub;
            const int wo = xh * 64 + pl;
            const int obase = ((b * 18 + 2 * k) * H_ + ho) * W_ + wo;
            const float dy = offset[obase];
            const float dx = offset[obase + HW];
            const float mm = mask[((b * 9 + k) * H_ + ho) * W_ + wo];
            const float py  = dy + (float)(k / 3) + (float)(ho - 1);
            const float pxx = dx + (float)(k % 3) + (float)(wo - 1);
            const float y0f = floorf(py), x0f = floorf(pxx);
            const float wy = py - y0f, wx = pxx - x0f;
            const int y0 = (int)y0f, x0 = (int)x0f;
            const int y1 = y0 + 1,  x1 = x0 + 1;
            const bool vy0 = (y0 >= 0) & (y0 < H_), vy1 = (y1 >= 0) & (y1 < H_);
            const bool vx0 = (x0 >= 0) & (x0 < W_), vx1 = (x1 >= 0) & (x1 < W_);
            const int cy0 = min(max(y0, 0), H_-1), cy1 = min(max(y1, 0), H_-1);
            const int cx0 = min(max(x0, 0), W_-1), cx1 = min(max(x1, 0), W_-1);
            idxs[it][0] = (cy0 * W_ + cx0) << 6;
            idxs[it][1] = (cy0 * W_ + cx1) << 6;
            idxs[it][2] = (cy1 * W_ + cx0) << 6;
            idxs[it][3] = (cy1 * W_ + cx1) << 6;
            wts[it][0] = (vy0 && vx0) ? (1.f - wy) * (1.f - wx) * mm : 0.f;
            wts[it][1] = (vy0 && vx1) ? (1.f - wy) * wx * mm         : 0.f;
            wts[it][2] = (vy1 && vx0) ? wy * (1.f - wx) * mm         : 0.f;
            wts[it][3] = (vy1 && vx1) ? wy * wx * mm                 : 0.f;
        }

        // ---- issue all 16 corner loads (8B/lane, 4 consecutive px/inst) ----
        bf16x4 cr[4][4];
        #pragma unroll
        for (int it = 0; it < 4; ++it)
            #pragma unroll
            for (int cn = 0; cn < 4; ++cn)
                cr[it][cn] = *(const bf16x4*)(xTb + idxs[it][cn] + (c4 << 2));

        // ---- stage Wk for this tap ----
        #pragma unroll
        for (int q = 0; q < 2; ++q) {
            const int j  = q * 2048 + t * 8;
            const int co = j >> 6, c0 = j & 63;
            *(bf16x8*)&Wk[s][co][c0] = *(const bf16x8*)(wprep + k * 4096 + j);
        }

        // ---- bilinear combine + LDS write ----
        #pragma unroll
        for (int it = 0; it < 4; ++it) {
            const int pl = (cq << 4) | (it << 2) | px_sub;
            union { bf16x4 v; unsigned short u[4]; } pk;
            #pragma unroll
            for (int j = 0; j < 4; ++j) {
                const float v = wts[it][0] * bf2f((unsigned short)cr[it][0][j])
                              + wts[it][1] * bf2f((unsigned short)cr[it][1][j])
                              + wts[it][2] * bf2f((unsigned short)cr[it][2][j])
                              + wts[it][3] * bf2f((unsigned short)cr[it][3][j]);
                pk.u[j] = f2bf(v);
            }
            *(bf16x4*)&vP[s][pl][c4 << 2] = pk.v;
        }
    };

    auto domfma = [&](int s) {
        const int ra = cq * 16 + (lane & 15);
        const int kc = (lane >> 4) * 8;
        #pragma unroll
        for (int ks = 0; ks < 2; ++ks) {
            const int kcol = ks * 32 + kc;
            const bf16x8 a = *(const bf16x8*)&vP[s][ra][kcol];
            #pragma unroll
            for (int nt = 0; nt < 4; ++nt) {
                const bf16x8 bb = *(const bf16x8*)&Wk[s][nt * 16 + (lane & 15)][kcol];
                acc[nt] = __builtin_amdgcn_mfma_f32_16x16x32_bf16(a, bb, acc[nt], 0, 0, 0);
            }
        }
    };

    stage(0, 0);
    __syncthreads();
    for (int k = 0; k < 9; ++k) {
        const int s = k & 1;
        if (k < 8) stage(k + 1, s ^ 1);
        domfma(s);
        __syncthreads();
    }

    const int px0 = cq * 16 + (lane >> 4) * 4;
    #pragma unroll
    for (int nt = 0; nt < 4; ++nt) {
        const int co = nt * 16 + (lane & 15);
        const float bb = bias[co];
        float4 r;
        r.x = acc[nt][0] + bb;
        r.y = acc[nt][1] + bb;
        r.z = acc[nt][2] + bb;
        r.w = acc[nt][3] + bb;
        *(float4*)&out[(((size_t)b * COUT_ + co) * H_ + ho) * W_ + xh * 64 + px0] = r;
    }
}

// ---------------- fallback (R3 kernel, no workspace) ----------------
__global__ __launch_bounds__(256, 4)
void dcn_mfma_fb(const float* __restrict__ x,
                 const float* __restrict__ offset,
                 const float* __restrict__ mask,
                 const float* __restrict__ weight,
                 const float* __restrict__ bias,
                 float* __restrict__ out)
{
    __shared__ unsigned short vP[2][64][72];
    __shared__ unsigned short Wk[2][64][72];
    const int t   = threadIdx.x;
    const int bid = blockIdx.x;
    const int wk  = ((bid & 7) << 7) | (bid >> 3);
    const int xh  = wk & 1;
    const int ho  = (wk >> 1) & 127;
    const int b   = wk >> 8;
    const int p   = t & 63;
    const int wo  = xh * 64 + p;
    const int cq  = t >> 6;
    const int lane = t & 63;
    f32x4 acc[4];
    #pragma unroll
    for (int i = 0; i < 4; ++i) acc[i] = (f32x4){0.f, 0.f, 0.f, 0.f};
    const float* xb = x + (size_t)(b * CIN_ + cq * 16) * HW;

    auto stage = [&](int k, int s) {
        const int obase = ((b * 18 + 2 * k) * H_ + ho) * W_ + wo;
        const float dy = offset[obase];
        const float dx = offset[obase + HW];
        const float mm = mask[((b * 9 + k) * H_ + ho) * W_ + wo];
        const float py  = dy + (float)(k / 3) + (float)(ho - 1);
        const float pxx = dx + (float)(k % 3) + (float)(wo - 1);
        const float y0f = floorf(py), x0f = floorf(pxx);
        const float wy = py - y0f, wx = pxx - x0f;
        const int y0 = (int)y0f, x0 = (int)x0f;
        const int y1 = y0 + 1,  x1 = x0 + 1;
        const bool vy0 = (y0 >= 0) & (y0 < H_), vy1 = (y1 >= 0) & (y1 < H_);
        const bool vx0 = (x0 >= 0) & (x0 < W_), vx1 = (x1 >= 0) & (x1 < W_);
        const int cy0 = min(max(y0, 0), H_-1), cy1 = min(max(y1, 0), H_-1);
        const int cx0 = min(max(x0, 0), W_-1), cx1 = min(max(x1, 0), W_-1);
        const int i00 = cy0 * W_ + cx0, i01 = cy0 * W_ + cx1;
        const int i10 = cy1 * W_ + cx0, i11 = cy1 * W_ + cx1;
        const float w00 = (vy0 && vx0) ? (1.f - wy) * (1.f - wx) * mm : 0.f;
        const float w01 = (vy0 && vx1) ? (1.f - wy) * wx * mm         : 0.f;
        const float w10 = (vy1 && vx0) ? wy * (1.f - wx) * mm         : 0.f;
        const float w11 = (vy1 && vx1) ? wy * wx * mm                 : 0.f;
        {
            const int co = t >> 2;
            const int c0 = (t & 3) * 16;
            union { bf16x8 v; unsigned short u[8]; } pk0, pk1;
            #pragma unroll
            for (int i = 0; i < 8; ++i) {
                pk0.u[i] = f2bf(weight[co * KPOS + (c0 + i) * 9 + k]);
                pk1.u[i] = f2bf(weight[co * KPOS + (c0 + 8 + i) * 9 + k]);
            }
            *(bf16x8*)&Wk[s][co][c0]     = pk0.v;
            *(bf16x8*)&Wk[s][co][c0 + 8] = pk1.v;
        }
        float r[16][4];
        {
            const float* xp = xb;
            #pragma unroll
            for (int c = 0; c < 16; ++c) {
                r[c][0] = xp[i00]; r[c][1] = xp[i01];
                r[c][2] = xp[i10]; r[c][3] = xp[i11];
                xp += HW;
            }
        }
        union { bf16x8 v; unsigned short u[8]; } pk;
        #pragma unroll
        for (int cb = 0; cb < 16; cb += 8) {
            #pragma unroll
            for (int u = 0; u < 8; ++u) {
                const int c = cb + u;
                pk.u[u] = f2bf(w00 * r[c][0] + w01 * r[c][1]
                             + w10 * r[c][2] + w11 * r[c][3]);
            }
            *(bf16x8*)&vP[s][p][cq * 16 + cb] = pk.v;
        }
    };
    auto domfma = [&](int s) {
        const int ra = cq * 16 + (lane & 15);
        const int kc = (lane >> 4) * 8;
        #pragma unroll
        for (int ks = 0; ks < 2; ++ks) {
            const int kcol = ks * 32 + kc;
            const bf16x8 a = *(const bf16x8*)&vP[s][ra][kcol];
            #pragma unroll
            for (int nt = 0; nt < 4; ++nt) {
                const bf16x8 bb = *(const bf16x8*)&Wk[s][nt * 16 + (lane & 15)][kcol];
                acc[nt] = __builtin_amdgcn_mfma_f32_16x16x32_bf16(a, bb, acc[nt], 0, 0, 0);
            }
        }
    };
    stage(0, 0);
    __syncthreads();
    for (int k = 0; k < 9; ++k) {
        const int s = k & 1;
        if (k < 8) stage(k + 1, s ^ 1);
        domfma(s);
        __syncthreads();
    }
    const int px0 = cq * 16 + (lane >> 4) * 4;
    #pragma unroll
    for (int nt = 0; nt < 4; ++nt) {
        const int co = nt * 16 + (lane & 15);
        const float bb = bias[co];
        float4 r;
        r.x = acc[nt][0] + bb;
        r.y = acc[nt][1] + bb;
        r.z = acc[nt][2] + bb;
        r.w = acc[nt][3] + bb;
        *(float4*)&out[(((size_t)b * COUT_ + co) * H_ + ho) * W_ + xh * 64 + px0] = r;
    }
}

extern "C" void kernel_launch(void* const* d_in, const int* in_sizes, int n_in,
                              void* d_out, int out_size, void* d_ws, size_t ws_size,
                              hipStream_t stream)
{
    const float* x      = (const float*)d_in[0];
    const float* offset = (const float*)d_in[1];
    const float* mask   = (const float*)d_in[2];
    const float* weight = (const float*)d_in[3];
    const float* bias   = (const float*)d_in[4];
    float* out = (float*)d_out;

    dim3 block(256);
    dim3 grid(B_ * H_ * 2);

    if (ws_size >= WS_NEED) {
        unsigned short* xT    = (unsigned short*)d_ws;
        unsigned short* wprep = xT + XT_USHORTS;
        xpose_bf16<<<dim3(B_ * H_), block, 0, stream>>>(x, xT);
        prep_weight_bf16<<<dim3(144), block, 0, stream>>>(weight, wprep);
        dcn_mfma_nhwc<<<grid, block, 0, stream>>>(xT, offset, mask, bias, wprep, out);
    } else {
        dcn_mfma_fb<<<grid, block, 0, stream>>>(x, offset, mask, weight, bias, out);
    }
}

// Round 5
// 44.096 us; speedup vs baseline: 5.4316x; 1.1242x over previous
//
#include <hip/hip_runtime.h>

#define B_    4
#define CIN_  64
#define H_    128
#define W_    128
#define COUT_ 64
#define HW    (H_*W_)
#define KPOS  576

typedef __attribute__((ext_vector_type(8))) short bf16x8;
typedef __attribute__((ext_vector_type(4))) short bf16x4;
typedef __attribute__((ext_vector_type(4))) float f32x4;
typedef __attribute__((ext_vector_type(4))) _Float16 f16x4;

static __device__ __forceinline__ unsigned short f2bf(float f) {
    union { float f; unsigned u; } a; a.f = f;
    unsigned r = a.u + 0x7fffu + ((a.u >> 16) & 1u);   // RNE
    return (unsigned short)(r >> 16);
}
static __device__ __forceinline__ float bfl(unsigned u) {   // low bf16 -> f32
    union { unsigned x; float f; } a; a.x = u << 16; return a.f;
}
static __device__ __forceinline__ float bfh(unsigned u) {   // high bf16 -> f32
    union { unsigned x; float f; } a; a.x = u & 0xffff0000u; return a.f;
}

#define XT_USHORTS 4194304                       // B*HW*64 NHWC bf16 image
#define WP_USHORTS 36864                         // wt[k][co][c]
#define META_CNT   (B_*9*HW)                     // 589824
#define OFFS_BYTE  ((XT_USHORTS + WP_USHORTS) * 2)        // 8462336
#define WTS_BYTE   (OFFS_BYTE + META_CNT * 4)             // 10821632
#define WS_NEED3   ((size_t)(WTS_BYTE + META_CNT * 8))    // ~15.5 MB
#define WS_NEED2   ((size_t)OFFS_BYTE)                    // ~8.5 MB (R4 path)

// ---------------- prep: weight -> bf16, tap-major ----------------
__global__ void prep_weight_bf16(const float* __restrict__ w,
                                 unsigned short* __restrict__ wt)
{
    const int i = blockIdx.x * 256 + threadIdx.x;
    if (i >= 9 * 64 * 64) return;
    const int k  = i >> 12;
    const int r  = i & 4095;
    const int co = r >> 6;
    const int c  = r & 63;
    wt[i] = f2bf(w[co * KPOS + c * 9 + k]);
}

// ---------------- prep: x NCHW f32 -> NHWC bf16 ----------------
__global__ __launch_bounds__(256)
void xpose_bf16(const float* __restrict__ x, unsigned short* __restrict__ xT)
{
    __shared__ unsigned short ld[64 * 132];
    const int t   = threadIdx.x;
    const int blk = blockIdx.x;          // b*128 + y
    const int b   = blk >> 7;
    const int y   = blk & 127;
    const float* src = x + (size_t)b * 64 * HW + y * W_;
    #pragma unroll
    for (int i = 0; i < 8; ++i) {
        const int e4 = (t + i * 256) * 4;
        const int c  = e4 >> 7;
        const int x0 = e4 & 127;
        const float4 v = *(const float4*)(src + (size_t)c * HW + x0);
        unsigned short* d = &ld[c * 132 + x0];
        d[0] = f2bf(v.x); d[1] = f2bf(v.y); d[2] = f2bf(v.z); d[3] = f2bf(v.w);
    }
    __syncthreads();
    unsigned short* dst = xT + ((size_t)b * HW + (size_t)y * W_) * 64;
    #pragma unroll
    for (int i = 0; i < 4; ++i) {
        const int o    = (t + i * 256) * 8;
        const int xcol = o >> 6;
        const int c0   = o & 63;
        union { bf16x8 v; unsigned short u[8]; } pk;
        #pragma unroll
        for (int j = 0; j < 8; ++j) pk.u[j] = ld[(c0 + j) * 132 + xcol];
        *(bf16x8*)(dst + o) = pk.v;
    }
}

// ---------------- prep: sampling metadata per (b,tap,pixel) ----------------
// mOffs: packed clamped corners y0|y1<<8|x0<<16|x1<<24 ; mWts: 4 x f16 weights*mask
__global__ __launch_bounds__(256)
void prep_meta(const float* __restrict__ offset, const float* __restrict__ mask,
               unsigned* __restrict__ mOffs, f16x4* __restrict__ mWts)
{
    const int i = blockIdx.x * 256 + threadIdx.x;
    if (i >= META_CNT) return;
    const int gp = i & (HW - 1);
    const int bk = i >> 14;              // b*9 + k
    const int b  = bk / 9;
    const int k  = bk - b * 9;
    const int ho = gp >> 7, wo = gp & 127;
    const float dy = offset[(size_t)(b * 18 + 2 * k) * HW + gp];
    const float dx = offset[(size_t)(b * 18 + 2 * k + 1) * HW + gp];
    const float mm = mask[(size_t)bk * HW + gp];
    const float py  = dy + (float)(k / 3) + (float)(ho - 1);   // PAD=1
    const float pxx = dx + (float)(k % 3) + (float)(wo - 1);
    const float y0f = floorf(py), x0f = floorf(pxx);
    const float wy = py - y0f, wx = pxx - x0f;
    const int y0 = (int)y0f, x0 = (int)x0f;
    const int y1 = y0 + 1,  x1 = x0 + 1;
    const bool vy0 = (y0 >= 0) & (y0 < H_), vy1 = (y1 >= 0) & (y1 < H_);
    const bool vx0 = (x0 >= 0) & (x0 < W_), vx1 = (x1 >= 0) & (x1 < W_);
    const int cy0 = min(max(y0, 0), H_-1), cy1 = min(max(y1, 0), H_-1);
    const int cx0 = min(max(x0, 0), W_-1), cx1 = min(max(x1, 0), W_-1);
    mOffs[i] = (unsigned)cy0 | ((unsigned)cy1 << 8)
             | ((unsigned)cx0 << 16) | ((unsigned)cx1 << 24);
    f16x4 w;
    w[0] = (_Float16)((vy0 && vx0) ? (1.f - wy) * (1.f - wx) * mm : 0.f);
    w[1] = (_Float16)((vy0 && vx1) ? (1.f - wy) * wx * mm         : 0.f);
    w[2] = (_Float16)((vy1 && vx0) ? wy * (1.f - wx) * mm         : 0.f);
    w[3] = (_Float16)((vy1 && vx1) ? wy * wx * mm                 : 0.f);
    mWts[i] = w;
}

// ---------------- main: meta-fed NHWC gather + MFMA ----------------
// One block = 64 px x 64 cout. Wave layout: lane = pxl*4 + coct (16 px x 4 ch-octs),
// 2 channel passes of 32. Schedule per tap: ld(k+1) -> mfma(k) -> fin(k+1) -> bar.
__global__ __launch_bounds__(256, 4)
void dcn_mfma_meta(const unsigned short* __restrict__ xT,
                   const unsigned* __restrict__ mOffs,
                   const f16x4* __restrict__ mWts,
                   const float* __restrict__ bias,
                   const unsigned short* __restrict__ wprep,
                   float* __restrict__ out)
{
    __shared__ unsigned short vP[2][64][72];
    __shared__ unsigned short Wk[2][64][72];

    const int t   = threadIdx.x;
    const int bid = blockIdx.x;
    const int wk  = ((bid & 7) << 7) | (bid >> 3);   // XCD-chunked swizzle
    const int xh  = wk & 1;
    const int ho  = (wk >> 1) & 127;
    const int b   = wk >> 8;
    const int cq  = t >> 6;
    const int lane = t & 63;
    const int pxl  = lane >> 2;          // 0..15 pixel within wave tile
    const int coct = lane & 3;           // 0..3 channel oct

    f32x4 acc[4];
    #pragma unroll
    for (int i = 0; i < 4; ++i) acc[i] = (f32x4){0.f, 0.f, 0.f, 0.f};

    const unsigned short* xTb = xT + (size_t)b * HW * 64;
    const int gp    = ho * W_ + xh * 64 + cq * 16 + pxl;   // pixel in image
    const int mbase = (b * 9) << 14;

    // ---- load all 9 taps' metadata up front (registers, static index) ----
    unsigned pk9[9]; f16x4 wh9[9];
    #pragma unroll
    for (int k = 0; k < 9; ++k) {
        const int mi = mbase + (k << 14) + gp;
        pk9[k] = mOffs[mi];
        wh9[k] = mWts[mi];
    }

    bf16x8 cr[2][4];   // [pass][corner] in-flight gather regs

    auto ld = [&](int k) {
        const unsigned pk = pk9[k];
        const int y0c = pk & 255,        y1c = (pk >> 8) & 255;
        const int x0c = (pk >> 16) & 255, x1c = (int)(pk >> 24);
        const int cho = coct * 8;
        const int p00 = (((y0c << 7) | x0c) << 6) + cho;
        const int p01 = (((y0c << 7) | x1c) << 6) + cho;
        const int p10 = (((y1c << 7) | x0c) << 6) + cho;
        const int p11 = (((y1c << 7) | x1c) << 6) + cho;
        #pragma unroll
        for (int pass = 0; pass < 2; ++pass) {
            const int o = pass * 32;
            cr[pass][0] = *(const bf16x8*)(xTb + p00 + o);
            cr[pass][1] = *(const bf16x8*)(xTb + p01 + o);
            cr[pass][2] = *(const bf16x8*)(xTb + p10 + o);
            cr[pass][3] = *(const bf16x8*)(xTb + p11 + o);
        }
    };

    auto fin = [&](int k) {
        const int s = k & 1;
        // stage Wk tap k (2 x b128 per thread, coalesced from wprep)
        {
            const int j  = t * 8;
            *(bf16x8*)&Wk[s][j >> 6][j & 63] =
                *(const bf16x8*)(wprep + k * 4096 + j);
            const int j2 = 2048 + j;
            *(bf16x8*)&Wk[s][j2 >> 6][j2 & 63] =
                *(const bf16x8*)(wprep + k * 4096 + j2);
        }
        const float w0 = (float)wh9[k][0];
        const float w1 = (float)wh9[k][1];
        const float w2 = (float)wh9[k][2];
        const float w3 = (float)wh9[k][3];
        #pragma unroll
        for (int pass = 0; pass < 2; ++pass) {
            union { bf16x8 v; unsigned u[4]; } c0u, c1u, c2u, c3u;
            c0u.v = cr[pass][0]; c1u.v = cr[pass][1];
            c2u.v = cr[pass][2]; c3u.v = cr[pass][3];
            float o[8];
            #pragma unroll
            for (int jj = 0; jj < 4; ++jj) {
                o[2*jj]   = w0*bfl(c0u.u[jj]) + w1*bfl(c1u.u[jj])
                          + w2*bfl(c2u.u[jj]) + w3*bfl(c3u.u[jj]);
                o[2*jj+1] = w0*bfh(c0u.u[jj]) + w1*bfh(c1u.u[jj])
                          + w2*bfh(c2u.u[jj]) + w3*bfh(c3u.u[jj]);
            }
            union { bf16x8 v; unsigned short us[8]; } pko;
            #pragma unroll
            for (int m = 0; m < 8; ++m) pko.us[m] = f2bf(o[m]);
            *(bf16x8*)&vP[s][cq * 16 + pxl][pass * 32 + coct * 8] = pko.v;
        }
    };

    auto domfma = [&](int k) {
        const int s  = k & 1;
        const int ra = cq * 16 + (lane & 15);
        const int kc = (lane >> 4) * 8;
        #pragma unroll
        for (int ks = 0; ks < 2; ++ks) {
            const int kcol = ks * 32 + kc;
            const bf16x8 a = *(const bf16x8*)&vP[s][ra][kcol];
            #pragma unroll
            for (int nt = 0; nt < 4; ++nt) {
                const bf16x8 bb = *(const bf16x8*)&Wk[s][nt * 16 + (lane & 15)][kcol];
                acc[nt] = __builtin_amdgcn_mfma_f32_16x16x32_bf16(a, bb, acc[nt], 0, 0, 0);
            }
        }
    };

    ld(0);
    fin(0);
    __syncthreads();
    #pragma unroll
    for (int k = 0; k < 9; ++k) {
        if (k < 8) ld(k + 1);     // issue next tap's gather
        domfma(k);                // consume LDS tap k
        if (k < 8) fin(k + 1);    // wait loads, combine, write LDS
        __syncthreads();
    }

    const int px0 = cq * 16 + (lane >> 4) * 4;
    #pragma unroll
    for (int nt = 0; nt < 4; ++nt) {
        const int co = nt * 16 + (lane & 15);
        const float bb = bias[co];
        float4 r;
        r.x = acc[nt][0] + bb;
        r.y = acc[nt][1] + bb;
        r.z = acc[nt][2] + bb;
        r.w = acc[nt][3] + bb;
        *(float4*)&out[(((size_t)b * COUT_ + co) * H_ + ho) * W_ + xh * 64 + px0] = r;
    }
}

// ---------------- fallback: R4 kernel (ws too small for meta) ----------------
__global__ __launch_bounds__(256, 4)
void dcn_mfma_nhwc(const unsigned short* __restrict__ xT,
                   const float* __restrict__ offset,
                   const float* __restrict__ mask,
                   const float* __restrict__ bias,
                   const unsigned short* __restrict__ wprep,
                   float* __restrict__ out)
{
    __shared__ unsigned short vP[2][64][72];
    __shared__ unsigned short Wk[2][64][72];
    const int t   = threadIdx.x;
    const int bid = blockIdx.x;
    const int wk  = ((bid & 7) << 7) | (bid >> 3);
    const int xh  = wk & 1;
    const int ho  = (wk >> 1) & 127;
    const int b   = wk >> 8;
    const int cq  = t >> 6;
    const int lane = t & 63;
    const int px_sub = lane >> 4;
    const int c4     = lane & 15;
    f32x4 acc[4];
    #pragma unroll
    for (int i = 0; i < 4; ++i) acc[i] = (f32x4){0.f, 0.f, 0.f, 0.f};
    const unsigned short* xTb = xT + (size_t)b * HW * 64;

    auto stage = [&](int k, int s) {
        int   idxs[4][4];
        float wts [4][4];
        #pragma unroll
        for (int it = 0; it < 4; ++it) {
            const int pl = (cq << 4) | (it << 2) | px_sub;
            const int wo = xh * 64 + pl;
            const int obase = ((b * 18 + 2 * k) * H_ + ho) * W_ + wo;
            const float dy = offset[obase];
            const float dx = offset[obase + HW];
            const float mm = mask[((b * 9 + k) * H_ + ho) * W_ + wo];
            const float py  = dy + (float)(k / 3) + (float)(ho - 1);
            const float pxx = dx + (float)(k % 3) + (float)(wo - 1);
            const float y0f = floorf(py), x0f = floorf(pxx);
            const float wy = py - y0f, wx = pxx - x0f;
            const int y0 = (int)y0f, x0 = (int)x0f;
            const int y1 = y0 + 1,  x1 = x0 + 1;
            const bool vy0 = (y0 >= 0) & (y0 < H_), vy1 = (y1 >= 0) & (y1 < H_);
            const bool vx0 = (x0 >= 0) & (x0 < W_), vx1 = (x1 >= 0) & (x1 < W_);
            const int cy0 = min(max(y0, 0), H_-1), cy1 = min(max(y1, 0), H_-1);
            const int cx0 = min(max(x0, 0), W_-1), cx1 = min(max(x1, 0), W_-1);
            idxs[it][0] = (cy0 * W_ + cx0) << 6;
            idxs[it][1] = (cy0 * W_ + cx1) << 6;
            idxs[it][2] = (cy1 * W_ + cx0) << 6;
            idxs[it][3] = (cy1 * W_ + cx1) << 6;
            wts[it][0] = (vy0 && vx0) ? (1.f - wy) * (1.f - wx) * mm : 0.f;
            wts[it][1] = (vy0 && vx1) ? (1.f - wy) * wx * mm         : 0.f;
            wts[it][2] = (vy1 && vx0) ? wy * (1.f - wx) * mm         : 0.f;
            wts[it][3] = (vy1 && vx1) ? wy * wx * mm                 : 0.f;
        }
        bf16x4 cr[4][4];
        #pragma unroll
        for (int it = 0; it < 4; ++it)
            #pragma unroll
            for (int cn = 0; cn < 4; ++cn)
                cr[it][cn] = *(const bf16x4*)(xTb + idxs[it][cn] + (c4 << 2));
        #pragma unroll
        for (int q = 0; q < 2; ++q) {
            const int j  = q * 2048 + t * 8;
            *(bf16x8*)&Wk[s][j >> 6][j & 63] = *(const bf16x8*)(wprep + k * 4096 + j);
        }
        #pragma unroll
        for (int it = 0; it < 4; ++it) {
            const int pl = (cq << 4) | (it << 2) | px_sub;
            union { bf16x4 v; unsigned short u[4]; } pk;
            #pragma unroll
            for (int j = 0; j < 4; ++j) {
                union { short s; unsigned short u; } s0{cr[it][0][j]}, s1{cr[it][1][j]},
                                                     s2{cr[it][2][j]}, s3{cr[it][3][j]};
                const float v = wts[it][0] * bfl(s0.u) + wts[it][1] * bfl(s1.u)
                              + wts[it][2] * bfl(s2.u) + wts[it][3] * bfl(s3.u);
                pk.u[j] = f2bf(v);
            }
            *(bf16x4*)&vP[s][pl][c4 << 2] = pk.v;
        }
    };
    auto domfma = [&](int s) {
        const int ra = cq * 16 + (lane & 15);
        const int kc = (lane >> 4) * 8;
        #pragma unroll
        for (int ks = 0; ks < 2; ++ks) {
            const int kcol = ks * 32 + kc;
            const bf16x8 a = *(const bf16x8*)&vP[s][ra][kcol];
            #pragma unroll
            for (int nt = 0; nt < 4; ++nt) {
                const bf16x8 bb = *(const bf16x8*)&Wk[s][nt * 16 + (lane & 15)][kcol];
                acc[nt] = __builtin_amdgcn_mfma_f32_16x16x32_bf16(a, bb, acc[nt], 0, 0, 0);
            }
        }
    };
    stage(0, 0);
    __syncthreads();
    for (int k = 0; k < 9; ++k) {
        const int s = k & 1;
        if (k < 8) stage(k + 1, s ^ 1);
        domfma(s);
        __syncthreads();
    }
    const int px0 = cq * 16 + (lane >> 4) * 4;
    #pragma unroll
    for (int nt = 0; nt < 4; ++nt) {
        const int co = nt * 16 + (lane & 15);
        const float bb = bias[co];
        float4 r;
        r.x = acc[nt][0] + bb;
        r.y = acc[nt][1] + bb;
        r.z = acc[nt][2] + bb;
        r.w = acc[nt][3] + bb;
        *(float4*)&out[(((size_t)b * COUT_ + co) * H_ + ho) * W_ + xh * 64 + px0] = r;
    }
}

extern "C" void kernel_launch(void* const* d_in, const int* in_sizes, int n_in,
                              void* d_out, int out_size, void* d_ws, size_t ws_size,
                              hipStream_t stream)
{
    const float* x      = (const float*)d_in[0];
    const float* offset = (const float*)d_in[1];
    const float* mask   = (const float*)d_in[2];
    const float* weight = (const float*)d_in[3];
    const float* bias   = (const float*)d_in[4];
    float* out = (float*)d_out;

    dim3 block(256);
    dim3 grid(B_ * H_ * 2);

    unsigned short* xT    = (unsigned short*)d_ws;
    unsigned short* wprep = xT + XT_USHORTS;

    if (ws_size >= WS_NEED3) {
        unsigned* mOffs = (unsigned*)((char*)d_ws + OFFS_BYTE);
        f16x4*    mWts  = (f16x4*)  ((char*)d_ws + WTS_BYTE);
        xpose_bf16<<<dim3(B_ * H_), block, 0, stream>>>(x, xT);
        prep_weight_bf16<<<dim3(144), block, 0, stream>>>(weight, wprep);
        prep_meta<<<dim3(META_CNT / 256), block, 0, stream>>>(offset, mask, mOffs, mWts);
        dcn_mfma_meta<<<grid, block, 0, stream>>>(xT, mOffs, mWts, bias, wprep, out);
    } else {
        xpose_bf16<<<dim3(B_ * H_), block, 0, stream>>>(x, xT);
        prep_weight_bf16<<<dim3(144), block, 0, stream>>>(weight, wprep);
        dcn_mfma_nhwc<<<grid, block, 0, stream>>>(xT, offset, mask, bias, wprep, out);
    }
}